// Round 10
// baseline (143.683 us; speedup 1.0000x reference)
//
#include <hip/hip_runtime.h>
#include <hip/hip_bf16.h>

// RGCN fused: per-relation aggregate (gather, fp32 acc) -> MFMA GEMM (K=8*64=512).
// x/linear fp32 on device, fp32 out (established r1-r3). Round 10:
// r6-r9 invariance (row rate ~22G/s across VALU/occupancy/bytes changes) =>
// the block's barrier-chained staging phases keep VMEM queues empty.
// Fix: ONE merged pack kernel precomputes in d_ws:
//   wsB  = bf16 W B-fragments (64 KB)
//   mPack= per-edge (rel<<24|src), per-node PRE-SORTED by rel (4.8 MB)
//   ptr32= int32 row pointers (400 KB)
//   wsX  = bf16 x rows, 128 B each (12.8 MB)
// Fused kernel: no staging, no sort, ONE barrier. Each quad: ptr pair + 12
// metas direct from L2-hot packed arrays; dual-group pipeline = 24 row loads
// in flight per wave; sorted-run overwrite-flush accumulate; sync; MFMA.
// NPB=64, (512,4): 66.8 KB LDS -> 2 blocks/CU, 128-VGPR cap.

#define THREADS 512
#define NPB 64
#define KDIM 512
#define LDA 520
#define WFRAG (4 * 16 * 64 * 8)   // 32768 bf16 elems = 64 KB

typedef __attribute__((ext_vector_type(8))) short bf16x8;
typedef __attribute__((ext_vector_type(4))) float f32x4;

extern __shared__ __align__(16) char smem[];

__device__ __forceinline__ unsigned short f2bf(float f) {
  __hip_bfloat16 h = __float2bfloat16(f);
  return *reinterpret_cast<unsigned short*>(&h);
}

#define ACC_SW(accrow, r, vv)                                        \
  switch (r) {                                                       \
    case 0: accrow[0] += (vv); break; case 1: accrow[1] += (vv); break; \
    case 2: accrow[2] += (vv); break; case 3: accrow[3] += (vv); break; \
    case 4: accrow[4] += (vv); break; case 5: accrow[5] += (vv); break; \
    case 6: accrow[6] += (vv); break; default: accrow[7] += (vv); break; }

// ---- merged pack: W frags | x bf16 rows | ptr32 + per-node sorted metas ----
__global__ __launch_bounds__(256)
void pack_all(const void* __restrict__ wv, const void* __restrict__ xv,
              const int* __restrict__ p32, const int* __restrict__ i32,
              const int* __restrict__ t32,
              unsigned short* __restrict__ wsB,
              unsigned short* __restrict__ wsX,
              int* __restrict__ ptr32, unsigned* __restrict__ mPack,
              int nx, int nnodes) {
  const int lane = threadIdx.x & 63;
  const unsigned ww = ((const unsigned*)wv)[lane];
  const int exw = (int)((ww >> 7) & 0xFFu);
  const bool w_bf16 = __popcll(__ballot(exw >= 96 && exw < 160)) >= 48;
  const unsigned xw = ((const unsigned*)xv)[lane];
  const int exx = (int)((xw >> 7) & 0xFFu);
  const bool x_bf16 = __popcll(__ballot(exx >= 96 && exx < 160)) >= 48;
  const bool idx64 = (p32[1] == 0);

  const int tW = wsB ? WFRAG : 0;
  const int tX = wsX ? (nx + 7) / 8 : 0;
  const int tN = (ptr32 && mPack) ? (nnodes + 1) : 0;

  int gid = blockIdx.x * 256 + threadIdx.x;
  if (gid < tW) {
    const int i = gid;
    const int j  = i & 7;
    const int l  = (i >> 3) & 63;
    const int kt = (i >> 9) & 15;
    const int nt = i >> 13;
    const int k  = kt * 32 + (l >> 4) * 8 + j;
    const int n  = nt * 16 + (l & 15);
    float v;
    if (w_bf16) v = __bfloat162float(((const __hip_bfloat16*)wv)[k * 64 + n]);
    else        v = ((const float*)wv)[k * 64 + n];
    wsB[i] = f2bf(v);
    return;
  }
  gid -= tW;
  if (gid < tX) {
    const int base = gid * 8;
    if (base + 8 <= nx) {
      if (x_bf16) {
        *(uint4*)(wsX + base) = *(const uint4*)((const unsigned short*)xv + base);
      } else {
        const float4 a = *(const float4*)((const float*)xv + base);
        const float4 b = *(const float4*)((const float*)xv + base + 4);
        ushort4 lo, hi;
        lo.x = f2bf(a.x); lo.y = f2bf(a.y); lo.z = f2bf(a.z); lo.w = f2bf(a.w);
        hi.x = f2bf(b.x); hi.y = f2bf(b.y); hi.z = f2bf(b.z); hi.w = f2bf(b.w);
        *(ushort4*)(wsX + base)     = lo;
        *(ushort4*)(wsX + base + 4) = hi;
      }
    } else {
      for (int i = base; i < nx; ++i)
        wsX[i] = x_bf16 ? ((const unsigned short*)xv)[i]
                        : f2bf(((const float*)xv)[i]);
    }
    return;
  }
  gid -= tX;
  if (gid < tN) {
    const int n = gid;
    const int pn = idx64 ? p32[2 * n] : p32[n];
    ptr32[n] = pn;
    if (n < nnodes) {
      const int e1 = idx64 ? p32[2 * n + 2] : p32[n + 1];
      const int deg = e1 - pn;
      if (deg == 12) {
        unsigned a[12];
#pragma unroll
        for (int j = 0; j < 12; ++j) {
          const int e = pn + j;
          const unsigned s = (unsigned)(idx64 ? i32[2 * e] : i32[e]);
          const unsigned r = (unsigned)(idx64 ? t32[2 * e] : t32[e]);
          a[j] = s | (r << 24);
        }
        // odd-even sort by rel (top byte)
#pragma unroll
        for (int rr = 0; rr < 12; ++rr)
#pragma unroll
          for (int i = (rr & 1); i + 1 < 12; i += 2) {
            const unsigned lo = min(a[i], a[i + 1]);
            const unsigned hi = max(a[i], a[i + 1]);
            a[i] = lo; a[i + 1] = hi;
          }
#pragma unroll
        for (int j = 0; j < 12; ++j) mPack[pn + j] = a[j];
      } else {
        for (int e = pn; e < e1; ++e) {
          const unsigned s = (unsigned)(idx64 ? i32[2 * e] : i32[e]);
          const unsigned r = (unsigned)(idx64 ? t32[2 * e] : t32[e]);
          mPack[e] = s | (r << 24);
        }
      }
    }
  }
}

__global__ __launch_bounds__(THREADS, 4)   // VGPR<=128; LDS 66.8K -> 2 blk/CU
void rgcn_fused(const void* __restrict__ xv,
                const void* __restrict__ wv,
                const int* __restrict__ p32,
                const int* __restrict__ i32,
                const int* __restrict__ t32,
                const unsigned short* __restrict__ wsB,
                const unsigned short* __restrict__ wsX,
                const int* __restrict__ ptr32,
                const unsigned* __restrict__ mPack,
                float* __restrict__ out,
                int num_nodes) {
  __hip_bfloat16* aggS = (__hip_bfloat16*)smem;                 // [NPB][LDA]
  __hip_bfloat16* wtS  = aggS + NPB * LDA;                      // only if !wsB
  float* invS = (float*)(smem + (size_t)NPB * LDA * 2 +
                         (wsB ? 0 : (size_t)64 * LDA * 2));     // [NPB]

  const int tid   = threadIdx.x;
  const int lane  = tid & 63;
  const int wvid  = tid >> 6;              // 0..7
  const int node0 = blockIdx.x * NPB;

  const unsigned xword = ((const unsigned*)xv)[lane];
  const int exf = (int)((xword >> 7) & 0xFFu);
  const bool x_bf16 = __popcll(__ballot(exf >= 96 && exf < 160)) >= 48;
  const bool idx64 = (p32[1] == 0);
  const bool direct = (mPack != nullptr);   // implies ptr32

  if (!wsB) {  // fallback: stage W^T in LDS (rare)
    if (x_bf16) {
      const __hip_bfloat16* wb = (const __hip_bfloat16*)wv;
      for (int i = tid; i < KDIM * 64; i += THREADS)
        wtS[(i & 63) * LDA + (i >> 6)] = wb[i];
    } else {
      const float* wf = (const float*)wv;
      for (int i = tid; i < KDIM * 64; i += THREADS)
        wtS[(i & 63) * LDA + (i >> 6)] = __float2bfloat16(wf[i]);
    }
  }

  const int c16 = lane & 15;
  const int qd  = lane >> 4;

  // sorted-run overwrite-flush accumulate for one node's 12 sorted metas
  auto flushAcc = [&](int nl, const unsigned* m, const uint2* u) {
    unsigned short* dst0 = (unsigned short*)(aggS + nl * LDA) + 4 * c16;
    const ushort4 z4 = {0, 0, 0, 0};
#pragma unroll
    for (int r = 0; r < 8; ++r) *(ushort4*)(dst0 + r * 64) = z4;
    float4 cur = make_float4(0.f, 0.f, 0.f, 0.f);
    unsigned prev = 0xFFFFFFFFu;
#pragma unroll
    for (int j = 0; j < 12; ++j) {
      const unsigned rj = m[j] >> 24;
      const float mk = (rj == prev) ? 1.0f : 0.0f;
      cur.x = fmaf(cur.x, mk, __uint_as_float(u[j].x << 16));
      cur.y = fmaf(cur.y, mk, __uint_as_float(u[j].x & 0xFFFF0000u));
      cur.z = fmaf(cur.z, mk, __uint_as_float(u[j].y << 16));
      cur.w = fmaf(cur.w, mk, __uint_as_float(u[j].y & 0xFFFF0000u));
      ushort4 bb;
      bb.x = f2bf(cur.x); bb.y = f2bf(cur.y);
      bb.z = f2bf(cur.z); bb.w = f2bf(cur.w);
      *(ushort4*)(dst0 + rj * 64) = bb;
      prev = rj;
    }
  };

  // generic: full wave per node (any deg / OOR / missing ws tiers)
  auto genericGroup = [&](int nlb) {
#pragma unroll
    for (int t = 0; t < 4; ++t) {
      const int nl = nlb + t;
      const int node = node0 + nl;
      float a[8] = {0.f, 0.f, 0.f, 0.f, 0.f, 0.f, 0.f, 0.f};
      int d = 0;
      if (node < num_nodes) {
        int e0, e1;
        if (direct) { e0 = ptr32[node]; e1 = ptr32[node + 1]; }
        else {
          e0 = idx64 ? p32[2 * node]     : p32[node];
          e1 = idx64 ? p32[2 * node + 2] : p32[node + 1];
        }
        d = e1 - e0;
        for (int e = e0; e < e1; ++e) {
          unsigned mm;
          if (direct) mm = mPack[e];
          else
            mm = (unsigned)(idx64 ? i32[2 * e] : i32[e]) |
                 ((unsigned)(idx64 ? t32[2 * e] : t32[e]) << 24);
          const size_t off = (size_t)(mm & 0x00FFFFFFu) * 64 + lane;
          float vv;
          if (wsX) {
            vv = __uint_as_float((unsigned)wsX[off] << 16);
          } else {
            vv = x_bf16 ? __bfloat162float(((const __hip_bfloat16*)xv)[off])
                        : ((const float*)xv)[off];
          }
          const int r = __builtin_amdgcn_readfirstlane((int)(mm >> 24));
          ACC_SW(a, r, vv)
        }
      }
#pragma unroll
      for (int r = 0; r < 8; ++r)
        aggS[nl * LDA + r * 64 + lane] = __float2bfloat16(a[r]);
      if (lane == 0)
        invS[nl] = (d > 0 && node < num_nodes) ? 1.0f / (float)d : 0.0f;
    }
  };

  bool done = false;
  if (direct && wsX) {
    const int nlA = wvid * 8 + qd;       // group A node for this quad
    const int nlB = nlA + 4;             // group B node
    const int nodeA = node0 + nlA, nodeB = node0 + nlB;
    int e0A = 0, dA = 0, e0B = 0, dB = 0;
    if (nodeA < num_nodes) { e0A = ptr32[nodeA]; dA = ptr32[nodeA + 1] - e0A; }
    if (nodeB < num_nodes) { e0B = ptr32[nodeB]; dB = ptr32[nodeB + 1] - e0B; }
    if (__ballot(dA == 12 && dB == 12) == ~0ull) {
      // dual-group pipeline: 24 meta + 24 row loads in flight per wave
      unsigned mA[12], mB[12];
#pragma unroll
      for (int j = 0; j < 12; ++j) mA[j] = mPack[e0A + j];
#pragma unroll
      for (int j = 0; j < 12; ++j) mB[j] = mPack[e0B + j];
      uint2 uA[12], uB[12];
#pragma unroll
      for (int j = 0; j < 12; ++j)
        uA[j] = ((const uint2*)wsX)[(size_t)(mA[j] & 0x00FFFFFFu) * 16 + c16];
#pragma unroll
      for (int j = 0; j < 12; ++j)
        uB[j] = ((const uint2*)wsX)[(size_t)(mB[j] & 0x00FFFFFFu) * 16 + c16];
      __builtin_amdgcn_sched_barrier(0);
      flushAcc(nlA, mA, uA);
      flushAcc(nlB, mB, uB);
      if (c16 == 0) {
        invS[nlA] = 1.0f / 12.0f;
        invS[nlB] = 1.0f / 12.0f;
      }
      done = true;
    }
  }
  if (!done) {
    genericGroup(wvid * 8);
    genericGroup(wvid * 8 + 4);
  }

  __syncthreads();   // the ONE barrier

  // ---- MFMA: 8 waves x two 16x16 tiles; out[64x64] = agg @ Wcat ----
  const int mt  = wvid >> 1;
  const int nt0 = (wvid & 1) * 2;
  const int mi  = lane & 15;
  const int q4  = lane >> 4;
  const __hip_bfloat16* ap = aggS + (mt * 16 + mi) * LDA + q4 * 8;
  f32x4 c0 = {0.f, 0.f, 0.f, 0.f};
  f32x4 c1 = {0.f, 0.f, 0.f, 0.f};
  if (wsB) {
    const bf16x8* B = (const bf16x8*)wsB;
#pragma unroll
    for (int kt = 0; kt < KDIM / 32; ++kt) {
      const bf16x8 a  = *(const bf16x8*)(ap + kt * 32);
      const bf16x8 b0 = B[((nt0 + 0) * 16 + kt) * 64 + lane];
      const bf16x8 b1 = B[((nt0 + 1) * 16 + kt) * 64 + lane];
      c0 = __builtin_amdgcn_mfma_f32_16x16x32_bf16(a, b0, c0, 0, 0, 0);
      c1 = __builtin_amdgcn_mfma_f32_16x16x32_bf16(a, b1, c1, 0, 0, 0);
    }
  } else {
    const __hip_bfloat16* bp0 = wtS + ((nt0 + 0) * 16 + mi) * LDA + q4 * 8;
    const __hip_bfloat16* bp1 = wtS + ((nt0 + 1) * 16 + mi) * LDA + q4 * 8;
#pragma unroll
    for (int kt = 0; kt < KDIM / 32; ++kt) {
      const bf16x8 a  = *(const bf16x8*)(ap  + kt * 32);
      const bf16x8 b0 = *(const bf16x8*)(bp0 + kt * 32);
      const bf16x8 b1 = *(const bf16x8*)(bp1 + kt * 32);
      c0 = __builtin_amdgcn_mfma_f32_16x16x32_bf16(a, b0, c0, 0, 0, 0);
      c1 = __builtin_amdgcn_mfma_f32_16x16x32_bf16(a, b1, c1, 0, 0, 0);
    }
  }

  // D layout: col = lane&15, row = q4*4 + reg -> fp32 stores
#pragma unroll
  for (int i = 0; i < 4; ++i) {
    const int nl   = mt * 16 + q4 * 4 + i;
    const int node = node0 + nl;
    if (node < num_nodes) {
      const float s = invS[nl];
      out[(size_t)node * 64 + (nt0 + 0) * 16 + mi] = c0[i] * s;
      out[(size_t)node * 64 + (nt0 + 1) * 16 + mi] = c1[i] * s;
    }
  }
}

extern "C" void kernel_launch(void* const* d_in, const int* in_sizes, int n_in,
                              void* d_out, int out_size, void* d_ws, size_t ws_size,
                              hipStream_t stream) {
  const void* x   = d_in[0];
  const void* w   = d_in[1];
  const int*  ptr = (const int*)d_in[2];
  const int*  idx = (const int*)d_in[3];
  const int*  et  = (const int*)d_in[4];
  float*      out = (float*)d_out;

  const int num_nodes = in_sizes[0] / 64;   // x is [N, 64]
  const int nx = num_nodes * 64;
  const int E  = in_sizes[3];               // edge count

  // ws layout: wsB | mPack | ptr32 | wsX (tiers degrade if ws too small)
  const size_t offB = 0, szB = (size_t)WFRAG * 2;
  const size_t offM = offB + szB, szM = (size_t)E * 4;
  const size_t offP = (offM + szM + 15) & ~(size_t)15;
  const size_t szP  = (size_t)(num_nodes + 1) * 4;
  const size_t offX = (offP + szP + 15) & ~(size_t)15;
  const size_t szX  = (size_t)nx * 2;

  const bool haveB = d_ws && ws_size >= offB + szB;
  const bool haveM = d_ws && ws_size >= offP + szP;   // meta + ptr together
  const bool haveX = d_ws && ws_size >= offX + szX;

  char* wsc = (char*)d_ws;
  unsigned short* wsB  = haveB ? (unsigned short*)(wsc + offB) : nullptr;
  unsigned*       mP   = haveM ? (unsigned*)(wsc + offM)       : nullptr;
  int*            pt32 = haveM ? (int*)(wsc + offP)            : nullptr;
  unsigned short* wsX  = haveX ? (unsigned short*)(wsc + offX) : nullptr;

  const long long tW = haveB ? WFRAG : 0;
  const long long tX = haveX ? (nx + 7) / 8 : 0;
  const long long tN = haveM ? (num_nodes + 1) : 0;
  const long long total = tW + tX + tN;
  if (total > 0) {
    const int pblocks = (int)((total + 255) / 256);
    pack_all<<<pblocks, 256, 0, stream>>>(w, x, ptr, idx, et, wsB, wsX,
                                          pt32, mP, nx, num_nodes);
  }

  const size_t lds_bytes = (size_t)NPB * LDA * 2 +
                           (haveB ? 0 : (size_t)64 * LDA * 2) +
                           (size_t)NPB * sizeof(float);

  hipFuncSetAttribute((const void*)rgcn_fused,
                      hipFuncAttributeMaxDynamicSharedMemorySize,
                      (int)lds_bytes);

  const int nblocks = (num_nodes + NPB - 1) / NPB;
  rgcn_fused<<<nblocks, THREADS, lds_bytes, stream>>>(x, w, ptr, idx, et, wsB,
                                                      wsX, pt32, mP, out,
                                                      num_nodes);
}